// Round 3
// baseline (543.546 us; speedup 1.0000x reference)
//
#include <hip/hip_runtime.h>
#include <stdint.h>

#define H_DIM 2048
#define E_NUM 8
#define D_DIM 2048
#define NTOK 4096
#define BM 128
#define BN 128
#define BK 64
#define MAXTILES 71   // worst-case sum of ceil(cnt_e/128): 8192/128 + 7

typedef __bf16 bf16x8 __attribute__((ext_vector_type(8)));
typedef float f32x4 __attribute__((ext_vector_type(4)));

__device__ __forceinline__ unsigned short f2bf(float f) {
    union { float f; uint32_t u; } c; c.f = f;
    uint32_t r = (c.u + 0x7FFFu + ((c.u >> 16) & 1u)) >> 16;
    return (unsigned short)r;
}
__device__ __forceinline__ float bf2f(unsigned short h) {
    union { float f; uint32_t u; } c; c.u = ((uint32_t)h) << 16;
    return c.f;
}

// async global->LDS, 16B/lane; LDS dest = wave-uniform base + lane*16.
__device__ __forceinline__ void gl_lds16(const unsigned short* g, unsigned short* l) {
    __builtin_amdgcn_global_load_lds(
        (const __attribute__((address_space(1))) unsigned int*)g,
        (__attribute__((address_space(3))) unsigned int*)l, 16, 0, 0);
}

// ------- K1: router, wave-per-token, fused x -> bf16 conversion -------------
__global__ __launch_bounds__(256) void router_cvt_kernel(
    const float* __restrict__ x, const float* __restrict__ rw,
    const float* __restrict__ rb, int* __restrict__ counts,
    uint32_t* __restrict__ tok, float* __restrict__ gate,
    unsigned short* __restrict__ xb) {
    int t = (blockIdx.x * 256 + threadIdx.x) >> 6;  // token = global wave id
    int lane = threadIdx.x & 63;
    const float* xr = x + (size_t)t * H_DIM;
    unsigned short* xo = xb + (size_t)t * H_DIM;
    float p[E_NUM];
#pragma unroll
    for (int e = 0; e < E_NUM; e++) p[e] = 0.f;
#pragma unroll
    for (int pass = 0; pass < H_DIM / 256; pass++) {
        int h = pass * 256 + lane * 4;
        float4 v = *(const float4*)(xr + h);
        ushort4 o;
        o.x = f2bf(v.x); o.y = f2bf(v.y); o.z = f2bf(v.z); o.w = f2bf(v.w);
        *(ushort4*)(xo + h) = o;
        const float* r0 = rw + (size_t)h * E_NUM;
#pragma unroll
        for (int e = 0; e < E_NUM; e++)
            p[e] += v.x * r0[e] + v.y * r0[e + 8] + v.z * r0[e + 16] + v.w * r0[e + 24];
    }
#pragma unroll
    for (int e = 0; e < E_NUM; e++) {
#pragma unroll
        for (int off = 1; off < 64; off <<= 1) p[e] += __shfl_xor(p[e], off, 64);
    }
    if (lane == 0) {
        float l[E_NUM];
#pragma unroll
        for (int e = 0; e < E_NUM; e++) l[e] = p[e] + rb[e];
        int e0 = 0;
#pragma unroll
        for (int e = 1; e < E_NUM; e++) if (l[e] > l[e0]) e0 = e;
        int e1 = (e0 == 0) ? 1 : 0;
#pragma unroll
        for (int e = 0; e < E_NUM; e++) if (e != e0 && l[e] > l[e1]) e1 = e;
        float g0 = 1.f / (1.f + __expf(l[e1] - l[e0]));
        float g1 = 1.f - g0;
        int p0 = atomicAdd(&counts[e0], 1);
        tok[e0 * NTOK + p0] = (uint32_t)t;
        gate[e0 * NTOK + p0] = g0;
        int p1 = atomicAdd(&counts[e1], 1);
        tok[e1 * NTOK + p1] = (uint32_t)t | (1u << 16);
        gate[e1 * NTOK + p1] = g1;
    }
}

// ------- K1b: build compact (expert, m0) tile table from counts -------------
__global__ void build_tiles_kernel(const int* __restrict__ counts,
                                   int* __restrict__ ntiles,
                                   int2* __restrict__ tab) {
    if (threadIdx.x == 0 && blockIdx.x == 0) {
        int off = 0;
        for (int e = 0; e < E_NUM; e++) {       // expert-major: keeps B L2 locality
            int c = counts[e];
            for (int m0 = 0; m0 < c; m0 += BM) tab[off++] = make_int2(e, m0);
        }
        *ntiles = off;
    }
}

// ------- K2: fp32 [K][N] -> bf16 [N][K] transpose (64n x 128k tiles) --------
__global__ __launch_bounds__(256) void transpose_cvt_kernel(
    const float* __restrict__ src, unsigned short* __restrict__ dst,
    int K_, int N_) {
    __shared__ unsigned short t[64][136];       // [n][k], +8 pad (stride 272B, 16B-mult)
    size_t moff = (size_t)blockIdx.z * (size_t)K_ * N_;
    const float* s = src + moff;
    unsigned short* d = dst + moff;
    int n0 = blockIdx.x * 64, k0 = blockIdx.y * 128;
    int tid = threadIdx.x;
    int rr = tid >> 4;          // 0..15
    int c4 = (tid & 15) * 4;    // n offset (floats) in read phase
#pragma unroll
    for (int p = 0; p < 8; p++) {
        int k = p * 16 + rr;
        float4 v = *(const float4*)(s + (size_t)(k0 + k) * N_ + n0 + c4);
        t[c4 + 0][k] = f2bf(v.x);
        t[c4 + 1][k] = f2bf(v.y);
        t[c4 + 2][k] = f2bf(v.z);
        t[c4 + 3][k] = f2bf(v.w);
    }
    __syncthreads();
    int kc = (tid & 15) * 8;    // k offset in write phase: 16 lanes x 16B = 256B/row
#pragma unroll
    for (int p = 0; p < 4; p++) {
        int n = p * 16 + rr;
        uint4 v = *(const uint4*)&t[n][kc];
        *(uint4*)(d + (size_t)(n0 + n) * K_ + k0 + kc) = v;
    }
}

// ------- K3: grouped gathered expert GEMM + gelu + gate ---------------------
__global__ __launch_bounds__(256) void expert_gemm_kernel(
    const unsigned short* __restrict__ xb,   // [NTOK][H] bf16
    const unsigned short* __restrict__ ewT,  // [E][D][H] bf16
    const float* __restrict__ eb,            // [E][D]
    const int* __restrict__ counts,
    const int* __restrict__ ntiles,
    const int2* __restrict__ tab,
    const uint32_t* __restrict__ tok,
    const float* __restrict__ gate,
    unsigned short* __restrict__ Y)          // [NTOK][2][D] bf16
{
    if ((int)blockIdx.y >= *ntiles) return;
    int2 te = tab[blockIdx.y];
    int e = te.x, m0 = te.y;
    int cnt = counts[e];
    int n0 = blockIdx.x * BN;

    __shared__ unsigned short As[BM][BK];    // flat, XOR-swizzled chunks
    __shared__ unsigned short Bs[BN][BK];
    __shared__ uint32_t tok_s[BM];
    __shared__ float gate_s[BM];

    int tid = threadIdx.x;
    if (tid < BM) {
        int idx = m0 + tid;
        uint32_t tk = 0; float g = 0.f;
        if (idx < cnt) { tk = tok[e * NTOK + idx]; g = gate[e * NTOK + idx]; }
        tok_s[tid] = tk; gate_s[tid] = g;
    }
    __syncthreads();

    int lane = tid & 63;
    int wave = tid >> 6;
    // staging: per gl_lds instr, lane -> row srow (8 rows x 128B), chunk (lane&7);
    // fetch global chunk (lane&7)^srow so LDS slot c holds logical chunk c^row&7.
    int srow = lane >> 3;
    int scol = ((lane & 7) ^ srow) * 8;
    const unsigned short* bbase = ewT + (size_t)e * D_DIM * H_DIM;
    const unsigned short* aptr[4];
    const unsigned short* bptr[4];
    unsigned short* lA[4];
    unsigned short* lB[4];
#pragma unroll
    for (int u = 0; u < 4; u++) {
        int r = wave * 32 + u * 8 + srow;
        aptr[u] = xb + (size_t)(tok_s[r] & 0xFFFFu) * H_DIM + scol;
        bptr[u] = bbase + (size_t)(n0 + r) * H_DIM + scol;
        lA[u] = &As[wave * 32 + u * 8][0];
        lB[u] = &Bs[wave * 32 + u * 8][0];
    }

    int wm = (wave >> 1) * 64;
    int wn = (wave & 1) * 64;
    int row16 = lane & 15;
    int quad = lane >> 4;
    // precomputed swizzled frag offsets (bytes); ks=1 chunk = ks0 chunk ^ 4 -> ^64B
    int aoffA[4], aoffB[4];
#pragma unroll
    for (int i = 0; i < 4; i++) {
        int ra = wm + i * 16 + row16;
        aoffA[i] = ra * (BK * 2) + ((quad ^ (ra & 7)) * 16);
        int rb = wn + i * 16 + row16;
        aoffB[i] = rb * (BK * 2) + ((quad ^ (rb & 7)) * 16);
    }
    const char* pA = (const char*)&As[0][0];
    const char* pB = (const char*)&Bs[0][0];

    f32x4 acc[4][4];
#pragma unroll
    for (int i = 0; i < 4; i++)
#pragma unroll
        for (int j = 0; j < 4; j++) acc[i][j] = (f32x4)(0.f);

    for (int kk = 0; kk < H_DIM; kk += BK) {
        __syncthreads();
#pragma unroll
        for (int u = 0; u < 4; u++) gl_lds16(aptr[u] + kk, lA[u]);
#pragma unroll
        for (int u = 0; u < 4; u++) gl_lds16(bptr[u] + kk, lB[u]);
        __syncthreads();
        bf16x8 a0[4], b0[4], a1[4], b1[4];
#pragma unroll
        for (int i = 0; i < 4; i++) {
            a0[i] = *(const bf16x8*)(pA + aoffA[i]);
            b0[i] = *(const bf16x8*)(pB + aoffB[i]);
            a1[i] = *(const bf16x8*)(pA + (aoffA[i] ^ 64));
            b1[i] = *(const bf16x8*)(pB + (aoffB[i] ^ 64));
        }
#pragma unroll
        for (int i = 0; i < 4; i++)
#pragma unroll
            for (int j = 0; j < 4; j++)
                acc[i][j] = __builtin_amdgcn_mfma_f32_16x16x32_bf16(
                    a0[i], b0[j], acc[i][j], 0, 0, 0);
#pragma unroll
        for (int i = 0; i < 4; i++)
#pragma unroll
            for (int j = 0; j < 4; j++)
                acc[i][j] = __builtin_amdgcn_mfma_f32_16x16x32_bf16(
                    a1[i], b1[j], acc[i][j], 0, 0, 0);
    }

    // epilogue: bias + gelu(tanh form == v*sigmoid(2q)) * gate, scatter to Y
#pragma unroll
    for (int i = 0; i < 4; i++) {
        int rbase = wm + i * 16 + quad * 4;
#pragma unroll
        for (int j = 0; j < 4; j++) {
            int n = n0 + wn + j * 16 + row16;
            float bias = eb[e * D_DIM + n];
#pragma unroll
            for (int r = 0; r < 4; r++) {
                int lrow = rbase + r;
                if (m0 + lrow < cnt) {
                    uint32_t tk = tok_s[lrow];
                    float g = gate_s[lrow];
                    float v = acc[i][j][r] + bias;
                    float q = 0.7978845608028654f * (v + 0.044715f * v * v * v);
                    float gl = v / (1.f + __expf(-2.f * q));
                    int token = tk & 0xFFFF;
                    int slot = (tk >> 16) & 1;
                    Y[((size_t)token * 2 + slot) * D_DIM + n] = f2bf(g * gl);
                }
            }
        }
    }
}

// ------- K4: combine slot0+slot1 -> bf16 combined ---------------------------
__global__ __launch_bounds__(256) void combine_kernel(
    const unsigned short* __restrict__ Y, unsigned short* __restrict__ comb) {
    int i = blockIdx.x * 256 + threadIdx.x;  // over NTOK*D/8
    int t = i >> 8;
    int dc = (i & 255) * 8;
    uint4 u0 = *(const uint4*)(Y + (size_t)t * 2 * D_DIM + dc);
    uint4 u1 = *(const uint4*)(Y + ((size_t)t * 2 + 1) * D_DIM + dc);
    uint4 o;
    uint32_t* po = (uint32_t*)&o;
    const uint32_t* p0 = (const uint32_t*)&u0;
    const uint32_t* p1 = (const uint32_t*)&u1;
#pragma unroll
    for (int k = 0; k < 4; k++) {
        uint32_t a = p0[k], b = p1[k];
        float s0 = bf2f((unsigned short)(a & 0xFFFF)) + bf2f((unsigned short)(b & 0xFFFF));
        float s1 = bf2f((unsigned short)(a >> 16)) + bf2f((unsigned short)(b >> 16));
        po[k] = (uint32_t)f2bf(s0) | ((uint32_t)f2bf(s1) << 16);
    }
    *(uint4*)(comb + (size_t)t * D_DIM + dc) = o;
}

// ------- K5: output projection GEMM + bias -> fp32 out ----------------------
__global__ __launch_bounds__(256) void out_gemm_kernel(
    const unsigned short* __restrict__ comb,  // [NTOK][D] bf16
    const unsigned short* __restrict__ owT,   // [D][D] bf16
    const float* __restrict__ ob,
    float* __restrict__ out) {
    int m0 = blockIdx.y * BM, n0 = blockIdx.x * BN;
    __shared__ unsigned short As[BM][BK];
    __shared__ unsigned short Bs[BN][BK];
    int tid = threadIdx.x;
    int lane = tid & 63;
    int wave = tid >> 6;
    int srow = lane >> 3;
    int scol = ((lane & 7) ^ srow) * 8;
    const unsigned short* aptr[4];
    const unsigned short* bptr[4];
    unsigned short* lA[4];
    unsigned short* lB[4];
#pragma unroll
    for (int u = 0; u < 4; u++) {
        int r = wave * 32 + u * 8 + srow;
        aptr[u] = comb + (size_t)(m0 + r) * D_DIM + scol;
        bptr[u] = owT + (size_t)(n0 + r) * D_DIM + scol;
        lA[u] = &As[wave * 32 + u * 8][0];
        lB[u] = &Bs[wave * 32 + u * 8][0];
    }

    int wm = (wave >> 1) * 64;
    int wn = (wave & 1) * 64;
    int row16 = lane & 15;
    int quad = lane >> 4;
    int aoffA[4], aoffB[4];
#pragma unroll
    for (int i = 0; i < 4; i++) {
        int ra = wm + i * 16 + row16;
        aoffA[i] = ra * (BK * 2) + ((quad ^ (ra & 7)) * 16);
        int rb = wn + i * 16 + row16;
        aoffB[i] = rb * (BK * 2) + ((quad ^ (rb & 7)) * 16);
    }
    const char* pA = (const char*)&As[0][0];
    const char* pB = (const char*)&Bs[0][0];

    f32x4 acc[4][4];
#pragma unroll
    for (int i = 0; i < 4; i++)
#pragma unroll
        for (int j = 0; j < 4; j++) acc[i][j] = (f32x4)(0.f);

    for (int kk = 0; kk < D_DIM; kk += BK) {
        __syncthreads();
#pragma unroll
        for (int u = 0; u < 4; u++) gl_lds16(aptr[u] + kk, lA[u]);
#pragma unroll
        for (int u = 0; u < 4; u++) gl_lds16(bptr[u] + kk, lB[u]);
        __syncthreads();
        bf16x8 a0[4], b0[4], a1[4], b1[4];
#pragma unroll
        for (int i = 0; i < 4; i++) {
            a0[i] = *(const bf16x8*)(pA + aoffA[i]);
            b0[i] = *(const bf16x8*)(pB + aoffB[i]);
            a1[i] = *(const bf16x8*)(pA + (aoffA[i] ^ 64));
            b1[i] = *(const bf16x8*)(pB + (aoffB[i] ^ 64));
        }
#pragma unroll
        for (int i = 0; i < 4; i++)
#pragma unroll
            for (int j = 0; j < 4; j++)
                acc[i][j] = __builtin_amdgcn_mfma_f32_16x16x32_bf16(
                    a0[i], b0[j], acc[i][j], 0, 0, 0);
#pragma unroll
        for (int i = 0; i < 4; i++)
#pragma unroll
            for (int j = 0; j < 4; j++)
                acc[i][j] = __builtin_amdgcn_mfma_f32_16x16x32_bf16(
                    a1[i], b1[j], acc[i][j], 0, 0, 0);
    }

#pragma unroll
    for (int i = 0; i < 4; i++) {
        int rbase = m0 + wm + i * 16 + quad * 4;
#pragma unroll
        for (int j = 0; j < 4; j++) {
            int n = n0 + wn + j * 16 + row16;
            float bias = ob[n];
#pragma unroll
            for (int r = 0; r < 4; r++) {
                out[(size_t)(rbase + r) * D_DIM + n] = acc[i][j][r] + bias;
            }
        }
    }
}

extern "C" void kernel_launch(void* const* d_in, const int* in_sizes, int n_in,
                              void* d_out, int out_size, void* d_ws, size_t ws_size,
                              hipStream_t stream) {
    const float* x        = (const float*)d_in[0];  // [4096, 2048]
    const float* router_w = (const float*)d_in[1];  // [2048, 8]
    const float* router_b = (const float*)d_in[2];  // [8]
    const float* expert_w = (const float*)d_in[3];  // [8, 2048, 2048]
    const float* expert_b = (const float*)d_in[4];  // [8, 2048]
    const float* out_w    = (const float*)d_in[5];  // [2048, 2048]
    const float* out_b    = (const float*)d_in[6];  // [2048]
    float* out = (float*)d_out;                     // [4096, 2048]

    char* w = (char*)d_ws;
    int* counts = (int*)w;                          // @0, 32B
    int* ntiles = (int*)(w + 64);                   // @64
    int2* tab = (int2*)(w + 128);                   // @128, 72*8B
    uint32_t* tok = (uint32_t*)(w + 1024);
    float* gate = (float*)(w + 1024 + E_NUM * NTOK * 4);
    size_t off = 1024 + (size_t)2 * E_NUM * NTOK * 4;
    unsigned short* xb = (unsigned short*)(w + off);
    off += (size_t)NTOK * H_DIM * 2;
    unsigned short* ewT = (unsigned short*)(w + off);
    off += (size_t)E_NUM * H_DIM * D_DIM * 2;
    unsigned short* owT = (unsigned short*)(w + off);
    off += (size_t)D_DIM * D_DIM * 2;
    unsigned short* Y = (unsigned short*)(w + off);
    off += (size_t)NTOK * 2 * D_DIM * 2;
    unsigned short* comb = (unsigned short*)(w + off);

    hipMemsetAsync(d_ws, 0, 1024, stream);
    router_cvt_kernel<<<NTOK / 4, 256, 0, stream>>>(x, router_w, router_b,
                                                    counts, tok, gate, xb);
    build_tiles_kernel<<<1, 64, 0, stream>>>(counts, ntiles, tab);
    transpose_cvt_kernel<<<dim3(32, 16, 8), 256, 0, stream>>>(expert_w, ewT, H_DIM, D_DIM);
    transpose_cvt_kernel<<<dim3(32, 16, 1), 256, 0, stream>>>(out_w, owT, D_DIM, D_DIM);
    expert_gemm_kernel<<<dim3(16, MAXTILES), 256, 0, stream>>>(
        xb, ewT, expert_b, counts, ntiles, tab, tok, gate, Y);
    combine_kernel<<<NTOK * D_DIM / 8 / 256, 256, 0, stream>>>(Y, comb);
    out_gemm_kernel<<<dim3(16, 32), 256, 0, stream>>>(comb, owT, out_b, out);
}

// Round 4
// 529.188 us; speedup vs baseline: 1.0271x; 1.0271x over previous
//
#include <hip/hip_runtime.h>
#include <stdint.h>

#define H_DIM 2048
#define E_NUM 8
#define D_DIM 2048
#define NTOK 4096
#define BM 128
#define BN 128
#define BK 32

typedef __bf16 bf16x8 __attribute__((ext_vector_type(8)));
typedef float f32x4 __attribute__((ext_vector_type(4)));

__device__ __forceinline__ unsigned short f2bf(float f) {
    union { float f; uint32_t u; } c; c.f = f;
    uint32_t r = (c.u + 0x7FFFu + ((c.u >> 16) & 1u)) >> 16;
    return (unsigned short)r;
}
__device__ __forceinline__ float bf2f(unsigned short h) {
    union { float f; uint32_t u; } c; c.u = ((uint32_t)h) << 16;
    return c.f;
}

// async global->LDS, 16B/lane; LDS dest = wave-uniform base + lane*16.
__device__ __forceinline__ void gl_lds16(const unsigned short* g, unsigned short* l) {
    __builtin_amdgcn_global_load_lds(
        (const __attribute__((address_space(1))) unsigned int*)g,
        (__attribute__((address_space(3))) unsigned int*)l, 16, 0, 0);
}

// ------- K1: router, wave-per-token, fused x -> bf16 conversion -------------
__global__ __launch_bounds__(256) void router_cvt_kernel(
    const float* __restrict__ x, const float* __restrict__ rw,
    const float* __restrict__ rb, int* __restrict__ counts,
    uint32_t* __restrict__ tok, float* __restrict__ gate,
    unsigned short* __restrict__ xb) {
    int t = (blockIdx.x * 256 + threadIdx.x) >> 6;  // token = global wave id
    int lane = threadIdx.x & 63;
    const float* xr = x + (size_t)t * H_DIM;
    unsigned short* xo = xb + (size_t)t * H_DIM;
    float p[E_NUM];
#pragma unroll
    for (int e = 0; e < E_NUM; e++) p[e] = 0.f;
#pragma unroll
    for (int pass = 0; pass < H_DIM / 256; pass++) {
        int h = pass * 256 + lane * 4;
        float4 v = *(const float4*)(xr + h);
        ushort4 o;
        o.x = f2bf(v.x); o.y = f2bf(v.y); o.z = f2bf(v.z); o.w = f2bf(v.w);
        *(ushort4*)(xo + h) = o;
        const float* r0 = rw + (size_t)h * E_NUM;
#pragma unroll
        for (int e = 0; e < E_NUM; e++)
            p[e] += v.x * r0[e] + v.y * r0[e + 8] + v.z * r0[e + 16] + v.w * r0[e + 24];
    }
#pragma unroll
    for (int e = 0; e < E_NUM; e++) {
#pragma unroll
        for (int off = 1; off < 64; off <<= 1) p[e] += __shfl_xor(p[e], off, 64);
    }
    if (lane == 0) {
        float l[E_NUM];
#pragma unroll
        for (int e = 0; e < E_NUM; e++) l[e] = p[e] + rb[e];
        int e0 = 0;
#pragma unroll
        for (int e = 1; e < E_NUM; e++) if (l[e] > l[e0]) e0 = e;
        int e1 = (e0 == 0) ? 1 : 0;
#pragma unroll
        for (int e = 0; e < E_NUM; e++) if (e != e0 && l[e] > l[e1]) e1 = e;
        float g0 = 1.f / (1.f + __expf(l[e1] - l[e0]));
        float g1 = 1.f - g0;
        int p0 = atomicAdd(&counts[e0], 1);
        tok[e0 * NTOK + p0] = (uint32_t)t;
        gate[e0 * NTOK + p0] = g0;
        int p1 = atomicAdd(&counts[e1], 1);
        tok[e1 * NTOK + p1] = (uint32_t)t | (1u << 16);
        gate[e1 * NTOK + p1] = g1;
    }
}

// ------- K2: fused fp32 [K][N] -> bf16 [N][K] transpose for ew + ow ---------
// z<8: expert z; z==8: out_w (owT is contiguous after ewT in ws).
__global__ __launch_bounds__(256) void transpose_cvt_kernel(
    const float* __restrict__ ew, const float* __restrict__ ow,
    unsigned short* __restrict__ ewT) {
    __shared__ unsigned short t[64][136];       // [n][k], +8 pad
    int z = blockIdx.z;
    const float* s = (z < 8) ? (ew + (size_t)z * H_DIM * D_DIM) : ow;
    unsigned short* d = ewT + (size_t)z * H_DIM * D_DIM;
    int n0 = blockIdx.x * 64, k0 = blockIdx.y * 128;
    int tid = threadIdx.x;
    int rr = tid >> 4;          // 0..15
    int c4 = (tid & 15) * 4;    // n offset (floats) in read phase
#pragma unroll
    for (int p = 0; p < 8; p++) {
        int k = p * 16 + rr;
        float4 v = *(const float4*)(s + (size_t)(k0 + k) * D_DIM + n0 + c4);
        t[c4 + 0][k] = f2bf(v.x);
        t[c4 + 1][k] = f2bf(v.y);
        t[c4 + 2][k] = f2bf(v.z);
        t[c4 + 3][k] = f2bf(v.w);
    }
    __syncthreads();
    int kc = (tid & 15) * 8;    // k offset in write phase: 16 lanes x 16B
#pragma unroll
    for (int p = 0; p < 4; p++) {
        int n = p * 16 + rr;
        uint4 v = *(const uint4*)&t[n][kc];
        *(uint4*)(d + (size_t)(n0 + n) * H_DIM + k0 + kc) = v;
    }
}

// ------- K3: grouped gathered expert GEMM + gelu + gate ---------------------
__global__ __launch_bounds__(256) void expert_gemm_kernel(
    const unsigned short* __restrict__ xb,   // [NTOK][H] bf16
    const unsigned short* __restrict__ ewT,  // [E][D][H] bf16
    const float* __restrict__ eb,            // [E][D]
    const int* __restrict__ counts,
    const uint32_t* __restrict__ tok,
    const float* __restrict__ gate,
    unsigned short* __restrict__ Y)          // [NTOK][2][D] bf16
{
    int e = blockIdx.z;
    int cnt = counts[e];
    int m0 = blockIdx.y * BM;
    if (m0 >= cnt) return;
    int n0 = blockIdx.x * BN;

    __shared__ unsigned short As[BM][BK];    // flat, chunk-swizzled by (row>>1)&3
    __shared__ unsigned short Bs[BN][BK];
    __shared__ uint32_t tok_s[BM];
    __shared__ float gate_s[BM];

    int tid = threadIdx.x;
    if (tid < BM) {
        int idx = m0 + tid;
        uint32_t tk = 0; float g = 0.f;
        if (idx < cnt) { tk = tok[e * NTOK + idx]; g = gate[e * NTOK + idx]; }
        tok_s[tid] = tk; gate_s[tid] = g;
    }
    __syncthreads();

    int lane = tid & 63;
    int wave = tid >> 6;
    // staging: lane -> row lane>>2 (16 rows x 64B per instr), LDS slot lane&3;
    // fetch global chunk (lane&3)^((lane>>3)&3) so logical chunk c of row r
    // lands at slot c^((r>>1)&3)  ->  conflict-free b128 frag reads.
    int sr = lane >> 2;
    int sc = ((lane & 3) ^ ((lane >> 3) & 3)) * 8;
    int r0 = wave * 32 + sr;
    int r1 = wave * 32 + 16 + sr;
    const unsigned short* agp0 = xb + (size_t)(tok_s[r0] & 0xFFFFu) * H_DIM + sc;
    const unsigned short* agp1 = xb + (size_t)(tok_s[r1] & 0xFFFFu) * H_DIM + sc;
    const unsigned short* bbase = ewT + (size_t)e * D_DIM * H_DIM;
    const unsigned short* bgp0 = bbase + (size_t)(n0 + r0) * H_DIM + sc;
    const unsigned short* bgp1 = bbase + (size_t)(n0 + r1) * H_DIM + sc;
    unsigned short* la0 = &As[wave * 32][0];
    unsigned short* la1 = &As[wave * 32 + 16][0];
    unsigned short* lb0 = &Bs[wave * 32][0];
    unsigned short* lb1 = &Bs[wave * 32 + 16][0];

    int wm = (wave >> 1) * 64;
    int wn = (wave & 1) * 64;
    int row16 = lane & 15;
    int quad = lane >> 4;
    int slot = (quad ^ ((row16 >> 1) & 3)) * 16;   // bytes
    int aoffA[4], aoffB[4];
#pragma unroll
    for (int i = 0; i < 4; i++) {
        aoffA[i] = (wm + i * 16 + row16) * (BK * 2) + slot;
        aoffB[i] = (wn + i * 16 + row16) * (BK * 2) + slot;
    }
    const char* pA = (const char*)&As[0][0];
    const char* pB = (const char*)&Bs[0][0];

    f32x4 acc[4][4];
#pragma unroll
    for (int i = 0; i < 4; i++)
#pragma unroll
        for (int j = 0; j < 4; j++) acc[i][j] = (f32x4)(0.f);

    for (int kk = 0; kk < H_DIM; kk += BK) {
        __syncthreads();                 // prior ds_reads done before overwrite
        gl_lds16(agp0 + kk, la0);
        gl_lds16(agp1 + kk, la1);
        gl_lds16(bgp0 + kk, lb0);
        gl_lds16(bgp1 + kk, lb1);
        __syncthreads();                 // drain -> tiles visible
        bf16x8 af[4], bff[4];
#pragma unroll
        for (int i = 0; i < 4; i++) {
            af[i] = *(const bf16x8*)(pA + aoffA[i]);
            bff[i] = *(const bf16x8*)(pB + aoffB[i]);
        }
#pragma unroll
        for (int i = 0; i < 4; i++)
#pragma unroll
            for (int j = 0; j < 4; j++)
                acc[i][j] = __builtin_amdgcn_mfma_f32_16x16x32_bf16(
                    af[i], bff[j], acc[i][j], 0, 0, 0);
    }

    // epilogue: bias + gelu(tanh form == v*sigmoid(2q)) * gate, scatter to Y
#pragma unroll
    for (int i = 0; i < 4; i++) {
        int rbase = wm + i * 16 + quad * 4;
#pragma unroll
        for (int j = 0; j < 4; j++) {
            int n = n0 + wn + j * 16 + row16;
            float bias = eb[e * D_DIM + n];
#pragma unroll
            for (int r = 0; r < 4; r++) {
                int lrow = rbase + r;
                if (m0 + lrow < cnt) {
                    uint32_t tk = tok_s[lrow];
                    float g = gate_s[lrow];
                    float v = acc[i][j][r] + bias;
                    float q = 0.7978845608028654f * (v + 0.044715f * v * v * v);
                    float gl = v / (1.f + __expf(-2.f * q));
                    int token = tk & 0xFFFF;
                    int slot2 = (tk >> 16) & 1;
                    Y[((size_t)token * 2 + slot2) * D_DIM + n] = f2bf(g * gl);
                }
            }
        }
    }
}

// ------- K4: combine slot0+slot1 -> bf16 combined ---------------------------
__global__ __launch_bounds__(256) void combine_kernel(
    const unsigned short* __restrict__ Y, unsigned short* __restrict__ comb) {
    int i = blockIdx.x * 256 + threadIdx.x;  // over NTOK*D/8
    int t = i >> 8;
    int dc = (i & 255) * 8;
    uint4 u0 = *(const uint4*)(Y + (size_t)t * 2 * D_DIM + dc);
    uint4 u1 = *(const uint4*)(Y + ((size_t)t * 2 + 1) * D_DIM + dc);
    uint4 o;
    uint32_t* po = (uint32_t*)&o;
    const uint32_t* p0 = (const uint32_t*)&u0;
    const uint32_t* p1 = (const uint32_t*)&u1;
#pragma unroll
    for (int k = 0; k < 4; k++) {
        uint32_t a = p0[k], b = p1[k];
        float s0 = bf2f((unsigned short)(a & 0xFFFF)) + bf2f((unsigned short)(b & 0xFFFF));
        float s1 = bf2f((unsigned short)(a >> 16)) + bf2f((unsigned short)(b >> 16));
        po[k] = (uint32_t)f2bf(s0) | ((uint32_t)f2bf(s1) << 16);
    }
    *(uint4*)(comb + (size_t)t * D_DIM + dc) = o;
}

// ------- K5: output projection GEMM + bias -> fp32 out ----------------------
__global__ __launch_bounds__(256) void out_gemm_kernel(
    const unsigned short* __restrict__ comb,  // [NTOK][D] bf16
    const unsigned short* __restrict__ owT,   // [D][D] bf16
    const float* __restrict__ ob,
    float* __restrict__ out) {
    int m0 = blockIdx.y * BM, n0 = blockIdx.x * BN;
    __shared__ unsigned short As[BM][BK];
    __shared__ unsigned short Bs[BN][BK];
    int tid = threadIdx.x;
    int lane = tid & 63;
    int wave = tid >> 6;
    int sr = lane >> 2;
    int sc = ((lane & 3) ^ ((lane >> 3) & 3)) * 8;
    int r0 = wave * 32 + sr;
    int r1 = wave * 32 + 16 + sr;
    const unsigned short* agp0 = comb + (size_t)(m0 + r0) * D_DIM + sc;
    const unsigned short* agp1 = comb + (size_t)(m0 + r1) * D_DIM + sc;
    const unsigned short* bgp0 = owT + (size_t)(n0 + r0) * D_DIM + sc;
    const unsigned short* bgp1 = owT + (size_t)(n0 + r1) * D_DIM + sc;
    unsigned short* la0 = &As[wave * 32][0];
    unsigned short* la1 = &As[wave * 32 + 16][0];
    unsigned short* lb0 = &Bs[wave * 32][0];
    unsigned short* lb1 = &Bs[wave * 32 + 16][0];

    int wm = (wave >> 1) * 64;
    int wn = (wave & 1) * 64;
    int row16 = lane & 15;
    int quad = lane >> 4;
    int slot = (quad ^ ((row16 >> 1) & 3)) * 16;
    int aoffA[4], aoffB[4];
#pragma unroll
    for (int i = 0; i < 4; i++) {
        aoffA[i] = (wm + i * 16 + row16) * (BK * 2) + slot;
        aoffB[i] = (wn + i * 16 + row16) * (BK * 2) + slot;
    }
    const char* pA = (const char*)&As[0][0];
    const char* pB = (const char*)&Bs[0][0];

    f32x4 acc[4][4];
#pragma unroll
    for (int i = 0; i < 4; i++)
#pragma unroll
        for (int j = 0; j < 4; j++) acc[i][j] = (f32x4)(0.f);

    for (int kk = 0; kk < D_DIM; kk += BK) {
        __syncthreads();
        gl_lds16(agp0 + kk, la0);
        gl_lds16(agp1 + kk, la1);
        gl_lds16(bgp0 + kk, lb0);
        gl_lds16(bgp1 + kk, lb1);
        __syncthreads();
        bf16x8 af[4], bff[4];
#pragma unroll
        for (int i = 0; i < 4; i++) {
            af[i] = *(const bf16x8*)(pA + aoffA[i]);
            bff[i] = *(const bf16x8*)(pB + aoffB[i]);
        }
#pragma unroll
        for (int i = 0; i < 4; i++)
#pragma unroll
            for (int j = 0; j < 4; j++)
                acc[i][j] = __builtin_amdgcn_mfma_f32_16x16x32_bf16(
                    af[i], bff[j], acc[i][j], 0, 0, 0);
    }

#pragma unroll
    for (int i = 0; i < 4; i++) {
        int rbase = m0 + wm + i * 16 + quad * 4;
#pragma unroll
        for (int j = 0; j < 4; j++) {
            int n = n0 + wn + j * 16 + row16;
            float bias = ob[n];
#pragma unroll
            for (int r = 0; r < 4; r++) {
                out[(size_t)(rbase + r) * D_DIM + n] = acc[i][j][r] + bias;
            }
        }
    }
}

extern "C" void kernel_launch(void* const* d_in, const int* in_sizes, int n_in,
                              void* d_out, int out_size, void* d_ws, size_t ws_size,
                              hipStream_t stream) {
    const float* x        = (const float*)d_in[0];  // [4096, 2048]
    const float* router_w = (const float*)d_in[1];  // [2048, 8]
    const float* router_b = (const float*)d_in[2];  // [8]
    const float* expert_w = (const float*)d_in[3];  // [8, 2048, 2048]
    const float* expert_b = (const float*)d_in[4];  // [8, 2048]
    const float* out_w    = (const float*)d_in[5];  // [2048, 2048]
    const float* out_b    = (const float*)d_in[6];  // [2048]
    float* out = (float*)d_out;                     // [4096, 2048]

    char* w = (char*)d_ws;
    int* counts = (int*)w;                          // @0
    uint32_t* tok = (uint32_t*)(w + 1024);
    float* gate = (float*)(w + 1024 + E_NUM * NTOK * 4);
    size_t off = 1024 + (size_t)2 * E_NUM * NTOK * 4;
    unsigned short* xb = (unsigned short*)(w + off);
    off += (size_t)NTOK * H_DIM * 2;
    unsigned short* ewT = (unsigned short*)(w + off);     // [8][D][H]
    off += (size_t)E_NUM * H_DIM * D_DIM * 2;
    unsigned short* owT = (unsigned short*)(w + off);     // contiguous after ewT
    off += (size_t)D_DIM * D_DIM * 2;
    unsigned short* Y = (unsigned short*)(w + off);
    off += (size_t)NTOK * 2 * D_DIM * 2;
    unsigned short* comb = (unsigned short*)(w + off);

    hipMemsetAsync(d_ws, 0, 1024, stream);
    router_cvt_kernel<<<NTOK / 4, 256, 0, stream>>>(x, router_w, router_b,
                                                    counts, tok, gate, xb);
    transpose_cvt_kernel<<<dim3(32, 16, 9), 256, 0, stream>>>(expert_w, out_w, ewT);
    expert_gemm_kernel<<<dim3(16, 32, 8), 256, 0, stream>>>(
        xb, ewT, expert_b, counts, tok, gate, Y);
    combine_kernel<<<NTOK * D_DIM / 8 / 256, 256, 0, stream>>>(Y, comb);
    out_gemm_kernel<<<dim3(16, 32), 256, 0, stream>>>(comb, owT, out_b, out);
}